// Round 10
// baseline (110.739 us; speedup 1.0000x reference)
//
#include <hip/hip_runtime.h>
#include <hip/hip_bf16.h>

#define CIN 32
#define OCH 64
#define HH  256
#define WW  256
#define HW  (HH * WW)
#define BH  8                 // output rows per block
#define ROWB (258 * 64)       // 16512 B per LDS row-slot

typedef __bf16 bf16x8 __attribute__((ext_vector_type(8)));
typedef float  f32x4  __attribute__((ext_vector_type(4)));
typedef float  f32x16 __attribute__((ext_vector_type(16)));

// Fused 3x3 conv, r9 structure + NON-DRAINING loop barrier.
// The only change vs r9: per-iter __syncthreads() (which emits s_waitcnt
// vmcnt(0) -> drains the 64KB/block store stream every iteration, serializing
// HBM behind MFMA/LDS) is replaced by s_waitcnt lgkmcnt(0) + s_barrier.
// Stores/loads stay in flight across the barrier (T3/T4 counted-drain
// principle); the ds_write's load dependence is satisfied by the compiler's
// counted vmcnt (loads are older than the stores). Unlike r5's failed attempt:
// stores remain BEFORE the barrier (no acc liveness extension) and af stays
// at af[9][2] with LB(256,1) (no allocator cap / no spill).
__global__ __launch_bounds__(256, 1) void conv_fused_kernel(
        const float* __restrict__ x, const float* __restrict__ wgt,
        const float* __restrict__ bias, float* __restrict__ out) {
    // chunked XCD swizzle: 512 blocks, 64 consecutive nids per XCD.
    const int bid = blockIdx.x;
    const int nid = (bid & 7) * 64 + (bid >> 3);
    const int b   = nid >> 5;                    // 0..15
    const int h0  = (nid & 31) * BH;             // 0..248
    const int tid = threadIdx.x;
    const int l   = tid & 63, wid = tid >> 6;
    const int lw  = l & 31,  hi  = l >> 5;
    const int og  = wid & 1;                     // o-half
    const int wf  = wid >> 1;                    // w-half

    __shared__ __bf16 xs[4][258][CIN];           // 66,048 B ring of 4 row-slots
    char* lds = (char*)&xs[0][0][0];
    const float* xb = x + (size_t)b * CIN * HW;

    // zero the w-pad entries (wp=0 and wp=257) of all 4 slots
    if (tid < 32) {
        const int s = tid >> 3, k = tid & 7;
        const int wp = (k < 4) ? 0 : 257;
        *(f32x4*)(lds + s * ROWB + wp * 64 + (k & 3) * 16) = (f32x4){0, 0, 0, 0};
    }

    // ---- weights: af[t][ks][j] = wgt[og*32+lw][ c = ks*16 + hi*8 + j, tap t ]
    bf16x8 af[9][2];
    {
        const float* wrow = wgt + (size_t)(og * 32 + lw) * 288 + hi * 72;
#pragma unroll
        for (int ks = 0; ks < 2; ++ks)
#pragma unroll
            for (int t = 0; t < 9; ++t)
#pragma unroll
                for (int j = 0; j < 8; ++j)
                    af[t][ks][j] = (__bf16)wrow[ks * 144 + j * 9 + t];
    }
    // bias: transposed D -> every acc reg has the same o = og*32 + lw
    const float bsc = bias[og * 32 + lw];

    // ---- staging: wave wid stages channels wid*8..+7, lane covers w=4l..4l+3
    auto stage = [&](int row) {
        char* slot = lds + ((row + 1) & 3) * ROWB;
        if (row >= 0 && row < HH) {
            const float* rp = xb + (size_t)row * WW;
            f32x4 v[8];
#pragma unroll
            for (int j = 0; j < 8; ++j)
                v[j] = *(const f32x4*)(rp + (size_t)(wid * 8 + j) * HW + 4 * l);
#pragma unroll
            for (int p = 0; p < 4; ++p) {
                const int w = 4 * l + p;
                bf16x8 pk;
#pragma unroll
                for (int j = 0; j < 8; ++j) pk[j] = (__bf16)v[j][p];
                *(bf16x8*)(slot + (w + 1) * 64 + ((wid ^ ((w >> 1) & 3)) << 4)) = pk;
            }
        } else {
#pragma unroll
            for (int p = 0; p < 4; ++p) {
                const int w = 4 * l + p;
                *(f32x4*)(slot + (w + 1) * 64 + ((wid ^ ((w >> 1) & 3)) << 4)) =
                    (f32x4){0, 0, 0, 0};
            }
        }
    };

    stage(h0 - 1); stage(h0); stage(h0 + 1);

    // ---- B-read lane offsets (identical to r8/r9; conflict-free)
    int off6[3][2];
#pragma unroll
    for (int kw = 0; kw < 3; ++kw) {
        const int e = lw + kw;
        const int m = (e == 0) ? 3 : (((e - 1) >> 1) & 3);
#pragma unroll
        for (int ks = 0; ks < 2; ++ks)
            off6[kw][ks] = e * 64 + (((ks * 2 + hi) ^ m) << 4);
    }
    const int halfoff = wf * (128 * 64);

    __syncthreads();   // once; prologue only

    for (int i = 0; i < BH; ++i) {
        const int h  = h0 + i;
        const int nr = h + 2;
        const bool havenext = (i < BH - 1);
        const bool rok2 = havenext && (nr < HH);

        // (1) issue-early: f32x4 loads for row h+2 (consumed at step 4)
        f32x4 v[8];
#pragma unroll
        for (int j = 0; j < 8; ++j) v[j] = (f32x4){0, 0, 0, 0};
        if (rok2) {
            const float* rp = xb + (size_t)nr * WW;
#pragma unroll
            for (int j = 0; j < 8; ++j)
                v[j] = *(const f32x4*)(rp + (size_t)(wid * 8 + j) * HW + 4 * l);
        }

        // (2) MFMA (swapped operands -> transposed D): rows h-1..h+1
        const char* s0 = lds + ((h    ) & 3) * ROWB + halfoff;
        const char* s1 = lds + ((h + 1) & 3) * ROWB + halfoff;
        const char* s2 = lds + ((h + 2) & 3) * ROWB + halfoff;
        f32x16 acc[4];
#pragma unroll
        for (int t = 0; t < 4; ++t)
#pragma unroll
            for (int r = 0; r < 16; ++r) acc[t][r] = bsc;
#pragma unroll
        for (int t = 0; t < 4; ++t) {
#pragma unroll
            for (int kh = 0; kh < 3; ++kh) {
                const char* s = (kh == 0) ? s0 : (kh == 1) ? s1 : s2;
#pragma unroll
                for (int ks = 0; ks < 2; ++ks)
#pragma unroll
                    for (int kw = 0; kw < 3; ++kw) {
                        bf16x8 bf = *(const bf16x8*)(s + t * 2048 + off6[kw][ks]);
                        acc[t] = __builtin_amdgcn_mfma_f32_32x32x16_bf16(
                            bf, af[kh * 3 + kw][ks], acc[t], 0, 0, 0);
                    }
            }
        }

        // (3) store row h: lane owns o = og*32+lw; regs 4q..4q+3 = 4 consec w
        float* outb = out + ((size_t)b * OCH + og * 32 + lw) * HW +
                      (size_t)h * WW + wf * 128 + 4 * hi;
#pragma unroll
        for (int t = 0; t < 4; ++t)
#pragma unroll
            for (int q = 0; q < 4; ++q) {
                f32x4 val = { acc[t][4 * q], acc[t][4 * q + 1],
                              acc[t][4 * q + 2], acc[t][4 * q + 3] };
                *(f32x4*)(outb + t * 32 + 8 * q) = val;
            }

        // (4) write-late: cvt + ds_write row h+2 into slot (h+3)&3
        //     (compiler emits a COUNTED vmcnt for the v[] dependence: the 8
        //      loads are older than the 16 stores -> stores stay in flight)
        if (havenext) {
            char* slot = lds + ((nr + 1) & 3) * ROWB;
#pragma unroll
            for (int p = 0; p < 4; ++p) {
                const int w = 4 * l + p;
                bf16x8 pk;
#pragma unroll
                for (int j = 0; j < 8; ++j) pk[j] = (__bf16)v[j][p];
                *(bf16x8*)(slot + (w + 1) * 64 + ((wid ^ ((w >> 1) & 3)) << 4)) = pk;
            }
            // (5) NON-DRAINING barrier: LDS visibility only; vmcnt untouched
            __builtin_amdgcn_sched_barrier(0);
            asm volatile("s_waitcnt lgkmcnt(0)" ::: "memory");
            __builtin_amdgcn_s_barrier();
            __builtin_amdgcn_sched_barrier(0);
        }
    }
}

extern "C" void kernel_launch(void* const* d_in, const int* in_sizes, int n_in,
                              void* d_out, int out_size, void* d_ws, size_t ws_size,
                              hipStream_t stream) {
    const float* x    = (const float*)d_in[0];
    const float* w    = (const float*)d_in[1];
    const float* bias = (const float*)d_in[2];
    float* out = (float*)d_out;

    hipLaunchKernelGGL(conv_fused_kernel, dim3(512), dim3(256), 0, stream,
                       x, w, bias, out);
}